// Round 10
// baseline (1736.258 us; speedup 1.0000x reference)
//
#include <hip/hip_runtime.h>
#include <hip/hip_bf16.h>
#include <stdint.h>

typedef __attribute__((ext_vector_type(8))) __bf16 bf16x8;
typedef __attribute__((ext_vector_type(4))) float f32x4;
typedef __attribute__((ext_vector_type(4))) int   i32x4;

#define BM 128
#define BN 128
#define BK 64

// i8 GEMM v2: 128x128 block, K-tile 64, group = 2 tiles (128 = AWQ group), ring-4 LDS (64KB)
#define JBM 128
#define JBN 128
#define JBK 64

__device__ inline void gload_lds16(const void* g, void* l) {
    __builtin_amdgcn_global_load_lds(
        (const __attribute__((address_space(1))) uint32_t*)g,
        (__attribute__((address_space(3))) uint32_t*)l, 16, 0, 0);
}

// ---------------- pass 1a: X f32 -> per-row int8 + scale ----------------
__global__ __launch_bounds__(256)
void quant_x(const float* __restrict__ X, int8_t* __restrict__ Xq,
             float* __restrict__ sx, int K) {
    const int row = blockIdx.x;
    const int tid = threadIdx.x;
    const float* base = X + (size_t)row * K;
    __shared__ float wred[4];

    float am = 0.f;
    for (int b = tid * 16; b < K; b += 256 * 16) {
#pragma unroll
        for (int c = 0; c < 4; ++c) {
            const float4 v = *(const float4*)(base + b + c * 4);
            am = fmaxf(am, fmaxf(fmaxf(fabsf(v.x), fabsf(v.y)),
                                 fmaxf(fabsf(v.z), fabsf(v.w))));
        }
    }
#pragma unroll
    for (int off = 32; off >= 1; off >>= 1)
        am = fmaxf(am, __shfl_xor(am, off));
    if ((tid & 63) == 0) wred[tid >> 6] = am;
    __syncthreads();
    am = fmaxf(fmaxf(wred[0], wred[1]), fmaxf(wred[2], wred[3]));

    const float inv = am > 0.f ? 127.f / am : 0.f;
    for (int b = tid * 16; b < K; b += 256 * 16) {
        int w[4];
#pragma unroll
        for (int c = 0; c < 4; ++c) {
            const float4 v = *(const float4*)(base + b + c * 4);
            const int b0 = __float2int_rn(v.x * inv) & 0xFF;
            const int b1 = __float2int_rn(v.y * inv) & 0xFF;
            const int b2 = __float2int_rn(v.z * inv) & 0xFF;
            const int b3 = __float2int_rn(v.w * inv) & 0xFF;
            w[c] = b0 | (b1 << 8) | (b2 << 16) | (b3 << 24);
        }
        *(int4*)(Xq + (size_t)row * K + b) = make_int4(w[0], w[1], w[2], w[3]);
    }
    if (tid == 0) sx[row] = am > 0.f ? am / 127.f : 0.f;
}

// ---------------- pass 1b: W -> int8 (q - z), exact ----------------
__global__ __launch_bounds__(128)
void quant_w(const int* __restrict__ QW, const int* __restrict__ QZ,
             int8_t* __restrict__ Wq, int N, int K) {
    const int PQ = K >> 3, NG = K >> 7, ZS = (NG + 7) >> 3;
    const int o = blockIdx.x;
    const int c = threadIdx.x;            // 0..K/32-1
    const int g = c >> 2;
    const int zq = (QZ[(size_t)o * ZS + (g >> 3)] >> ((g & 7) * 4)) & 15;
    const int4 qv = *(const int4*)(QW + (size_t)o * PQ + c * 4);
    const int vs[4] = {qv.x, qv.y, qv.z, qv.w};
    int words[8];
#pragma unroll
    for (int w = 0; w < 4; ++w) {
        const int v = vs[w];
        int w0 = 0, w1 = 0;
#pragma unroll
        for (int j = 0; j < 4; ++j)
            w0 |= ((((v >> (4 * j)) & 15) - zq) & 0xFF) << (8 * j);
#pragma unroll
        for (int j = 0; j < 4; ++j)
            w1 |= ((((v >> (4 * (j + 4))) & 15) - zq) & 0xFF) << (8 * j);
        words[w * 2] = w0; words[w * 2 + 1] = w1;
    }
    int8_t* dst = Wq + (size_t)o * K + c * 32;
    *(int4*)dst        = make_int4(words[0], words[1], words[2], words[3]);
    *(int4*)(dst + 16) = make_int4(words[4], words[5], words[6], words[7]);
}

// ---------------- pass 1c: scales [O][NG] f32 -> [NG][O] ----------------
__global__ __launch_bounds__(256)
void tr_s(const float* __restrict__ S, float* __restrict__ St, int N, int NG) {
    const int idx = blockIdx.x * 256 + threadIdx.x;
    if (idx >= N * NG) return;
    const int g = idx / N, o = idx % N;
    St[idx] = S[(size_t)o * NG + g];
}

// ---------------- pass 2: i8 GEMM v2 ----------------
// 512 thr = 8 waves (2 wm x 4 wn), wave tile 64x32 = 4x2 frags.
// Ring-4 x (A 128x64 i8 8KB + B 128x64 8KB) = 64KB -> 2 blocks/CU (4 waves/SIMD).
// Group g = K-tiles 2g,2g+1 (128 K = one AWQ group); iacc accumulates over both
// tiles (exact), one f32 merge per group. Depth-2 prefetch; counted gates
// (FIFO-audited): even-top vmcnt(2), odd-top vmcnt(4), CVT vmcnt(4); full drain
// only in peeled last group. Read swizzle chunk^( (row>>1)&3 ) (r6: 0 conflicts),
// staging pre-swizzled at the global source, linear gload_lds dest.
__global__ __launch_bounds__(512, 4)
void gemm_i8v2(const int8_t* __restrict__ Aq, const float* __restrict__ sx,
               const int8_t* __restrict__ Bq, const float* __restrict__ St,
               const float* __restrict__ Bi, float* __restrict__ Out,
               int M, int N, int K) {
    __shared__ __align__(16) char lds[4 * 16384];

    const int tid  = threadIdx.x;
    const int lane = tid & 63;
    const int wid  = tid >> 6;
    const int wm   = wid >> 2;   // 0..1
    const int wn   = wid & 3;    // 0..3

    int bid = blockIdx.x;
    {
        const int nwg = gridDim.x;
        if ((nwg & 7) == 0) {
            const int cpx = nwg >> 3;
            bid = (bid & 7) * cpx + (bid >> 3);
        }
    }
    const int nbm  = M / JBM;
    const int brow = (bid % nbm) * JBM;   // col-major tile order
    const int bcol = (bid / nbm) * JBN;

    // staging: per matrix 512 16B-slots (1/thread). slot s: row=s>>2, c_lds=s&3,
    // global chunk c_g = (s&3) ^ ((s>>3)&3)   [row>>1 = s>>3]
    const int sro = tid >> 2;
    const int scg = (tid & 3) ^ ((tid >> 3) & 3);
    const int8_t* gA = Aq + (size_t)(brow + sro) * K + scg * 16;
    const int8_t* gB = Bq + (size_t)(bcol + sro) * K + scg * 16;
    const int lbA = wid * 1024;           // wave-uniform LDS byte base (HW adds lane*16)

    const int rA15 = lane & 15;
    const int q4   = lane >> 4;
    const int chunkoff = (q4 ^ ((rA15 >> 1) & 3)) * 16;

    f32x4 facc[4][2];
#pragma unroll
    for (int i = 0; i < 4; ++i) {
        facc[i][0] = {0.f, 0.f, 0.f, 0.f};
        facc[i][1] = {0.f, 0.f, 0.f, 0.f};
    }
    i32x4 iacc[4][2];
    float sv0 = 0.f, sv1 = 0.f;

    const int NGRP = K / 128;   // host guarantees even, >= 4

#define SBAR __builtin_amdgcn_sched_barrier(0)
#define ABUF(RR_) (lds + (RR_) * 16384)
#define BBUF(RR_) (lds + (RR_) * 16384 + 8192)

#define STAGE(RR_, T_)                                                   \
    do {                                                                 \
        gload_lds16(gA + (size_t)(T_) * JBK, ABUF(RR_) + lbA);           \
        gload_lds16(gB + (size_t)(T_) * JBK, BBUF(RR_) + lbA);           \
    } while (0)

#define LDA(RR_, MI) \
    (*(const i32x4*)(ABUF(RR_) + (wm * 64 + (MI) * 16 + rA15) * 64 + chunkoff))
#define LDB(RR_, NI) \
    (*(const i32x4*)(BBUF(RR_) + (wn * 32 + (NI) * 16 + rA15) * 64 + chunkoff))

#define MFMA8(RR_, FIRST_)                                               \
    do {                                                                 \
        i32x4 b0 = LDB(RR_, 0), b1 = LDB(RR_, 1);                        \
        i32x4 a0 = LDA(RR_, 0), a1 = LDA(RR_, 1);                        \
        i32x4 a2 = LDA(RR_, 2), a3 = LDA(RR_, 3);                        \
        asm volatile("s_waitcnt lgkmcnt(0)" ::: "memory"); SBAR;         \
        __builtin_amdgcn_s_setprio(1);                                   \
        if (FIRST_) {                                                    \
            const i32x4 zz = {0, 0, 0, 0};                               \
            iacc[0][0] = __builtin_amdgcn_mfma_i32_16x16x64_i8(a0, b0, zz, 0, 0, 0); \
            iacc[0][1] = __builtin_amdgcn_mfma_i32_16x16x64_i8(a0, b1, zz, 0, 0, 0); \
            iacc[1][0] = __builtin_amdgcn_mfma_i32_16x16x64_i8(a1, b0, zz, 0, 0, 0); \
            iacc[1][1] = __builtin_amdgcn_mfma_i32_16x16x64_i8(a1, b1, zz, 0, 0, 0); \
            iacc[2][0] = __builtin_amdgcn_mfma_i32_16x16x64_i8(a2, b0, zz, 0, 0, 0); \
            iacc[2][1] = __builtin_amdgcn_mfma_i32_16x16x64_i8(a2, b1, zz, 0, 0, 0); \
            iacc[3][0] = __builtin_amdgcn_mfma_i32_16x16x64_i8(a3, b0, zz, 0, 0, 0); \
            iacc[3][1] = __builtin_amdgcn_mfma_i32_16x16x64_i8(a3, b1, zz, 0, 0, 0); \
        } else {                                                         \
            iacc[0][0] = __builtin_amdgcn_mfma_i32_16x16x64_i8(a0, b0, iacc[0][0], 0, 0, 0); \
            iacc[0][1] = __builtin_amdgcn_mfma_i32_16x16x64_i8(a0, b1, iacc[0][1], 0, 0, 0); \
            iacc[1][0] = __builtin_amdgcn_mfma_i32_16x16x64_i8(a1, b0, iacc[1][0], 0, 0, 0); \
            iacc[1][1] = __builtin_amdgcn_mfma_i32_16x16x64_i8(a1, b1, iacc[1][1], 0, 0, 0); \
            iacc[2][0] = __builtin_amdgcn_mfma_i32_16x16x64_i8(a2, b0, iacc[2][0], 0, 0, 0); \
            iacc[2][1] = __builtin_amdgcn_mfma_i32_16x16x64_i8(a2, b1, iacc[2][1], 0, 0, 0); \
            iacc[3][0] = __builtin_amdgcn_mfma_i32_16x16x64_i8(a3, b0, iacc[3][0], 0, 0, 0); \
            iacc[3][1] = __builtin_amdgcn_mfma_i32_16x16x64_i8(a3, b1, iacc[3][1], 0, 0, 0); \
        }                                                                \
        __builtin_amdgcn_s_setprio(0); SBAR;                             \
    } while (0)

// GROUP: even tile (ring RE_) + odd tile (ring RO_) for group G_.
// S1_/S2_ stage future tiles; TOPE_/TOPO_/CVT_ are vmcnt literals (strings).
#define GROUP(RE_, RO_, G_, S1_, S2_, TOPE_, TOPO_, CVT_)                \
    do {                                                                 \
        asm volatile("s_waitcnt vmcnt(" TOPE_ ")" ::: "memory"); SBAR;   \
        __builtin_amdgcn_s_barrier(); SBAR;                              \
        {                                                                \
            const size_t so = (size_t)(G_) * N + bcol + wn * 32 + rA15;  \
            sv0 = St[so]; sv1 = St[so + 16];                             \
        }                                                                \
        SBAR; S1_; SBAR;                                                 \
        MFMA8(RE_, true);                                                \
        asm volatile("s_waitcnt vmcnt(" TOPO_ ")" ::: "memory"); SBAR;   \
        __builtin_amdgcn_s_barrier(); SBAR;                              \
        S2_; SBAR;                                                       \
        MFMA8(RO_, false);                                               \
        asm volatile("s_waitcnt vmcnt(" CVT_ ")" ::: "memory"); SBAR;    \
        _Pragma("unroll")                                                \
        for (int mi = 0; mi < 4; ++mi) {                                 \
            _Pragma("unroll")                                            \
            for (int j = 0; j < 4; ++j) {                                \
                facc[mi][0][j] += (float)iacc[mi][0][j] * sv0;           \
                facc[mi][1][j] += (float)iacc[mi][1][j] * sv1;           \
            }                                                            \
        }                                                                \
    } while (0)

    // prologue: tiles 0,1 in flight
    STAGE(0, 0);
    STAGE(1, 1);

    for (int g = 0; g < NGRP - 2; g += 2) {
        GROUP(0, 1, g,     STAGE(2, 2 * g + 2), STAGE(3, 2 * g + 3), "2", "4", "4");
        GROUP(2, 3, g + 1, STAGE(0, 2 * g + 4), STAGE(1, 2 * g + 5), "2", "4", "4");
    }
    GROUP(0, 1, NGRP - 2, STAGE(2, 2 * NGRP - 2), STAGE(3, 2 * NGRP - 1), "2", "4", "4");
    GROUP(2, 3, NGRP - 1, (void)0, (void)0, "2", "2", "0");

#undef GROUP
#undef MFMA8
#undef LDB
#undef LDA
#undef STAGE
#undef BBUF
#undef ABUF
#undef SBAR

    // epilogue: C frag col=lane&15, row=(lane>>4)*4+r; out = sx[row]*acc + bias
    const int cr0 = brow + wm * 64;
    const int cc0 = bcol + wn * 32;
    float sxr[4][4];
#pragma unroll
    for (int mi = 0; mi < 4; ++mi)
#pragma unroll
        for (int r = 0; r < 4; ++r)
            sxr[mi][r] = sx[cr0 + mi * 16 + q4 * 4 + r];
#pragma unroll
    for (int ni = 0; ni < 2; ++ni) {
        const int col = cc0 + ni * 16 + rA15;
        const float bv = Bi[col];
#pragma unroll
        for (int mi = 0; mi < 4; ++mi) {
#pragma unroll
            for (int r = 0; r < 4; ++r) {
                const int row = cr0 + mi * 16 + q4 * 4 + r;
                Out[(size_t)row * N + col] = sxr[mi][r] * facc[mi][ni][r] + bv;
            }
        }
    }
}

// ---------------- fallback: fused kernel (ws too small / odd shapes) ----------------
__global__ __launch_bounds__(256, 3)
void awq_gemm_fused(const float* __restrict__ X,
                    const int* __restrict__ QW,
                    const int* __restrict__ QZ,
                    const float* __restrict__ S,
                    const float* __restrict__ Bi,
                    float* __restrict__ Out,
                    int M, int N, int K) {
    const int PQ = K >> 3, NG = K >> 7, ZS = (NG + 7) >> 3;

    __shared__ __align__(16) __bf16 As[BM * BK];
    __shared__ __align__(16) __bf16 Bs[BN * BK];

    const int tid  = threadIdx.x;
    const int lane = tid & 63;
    const int wid  = tid >> 6;

    const int nwg = gridDim.x;
    int bid = blockIdx.x;
    if ((nwg & 7) == 0) {
        const int cpx = nwg >> 3;
        bid = (bid & 7) * cpx + (bid >> 3);
    }
    const int nbn  = N / BN;
    const int brow = (bid / nbn) * BM;
    const int bcol = (bid % nbn) * BN;

    const int wm = wid >> 1;
    const int wn = wid & 1;

    f32x4 acc[4][4];
#pragma unroll
    for (int i = 0; i < 4; ++i)
#pragma unroll
        for (int j = 0; j < 4; ++j)
            acc[i][j] = {0.f, 0.f, 0.f, 0.f};

    int arow[4], acch[4];
#pragma unroll
    for (int it = 0; it < 4; ++it) {
        const int idx = it * 256 + tid;
        arow[it] = idx >> 3;
        acch[it] = idx & 7;
    }

    const int rb    = tid >> 1;
    const int bhalf = tid & 1;
    const int og    = bcol + rb;
    const int* qwrow = QW + (size_t)og * PQ;
    const int* qzrow = QZ + (size_t)og * ZS;
    const float* srow = S + (size_t)og * NG;

    for (int kk = 0; kk < K; kk += BK) {
        bf16x8 areg[4];
#pragma unroll
        for (int it = 0; it < 4; ++it) {
            const float* gx = X + (size_t)(brow + arow[it]) * K + kk + acch[it] * 8;
            const float4 x0 = *(const float4*)gx;
            const float4 x1 = *(const float4*)(gx + 4);
            areg[it][0] = (__bf16)x0.x; areg[it][1] = (__bf16)x0.y;
            areg[it][2] = (__bf16)x0.z; areg[it][3] = (__bf16)x0.w;
            areg[it][4] = (__bf16)x1.x; areg[it][5] = (__bf16)x1.y;
            areg[it][6] = (__bf16)x1.z; areg[it][7] = (__bf16)x1.w;
        }

        const int4 qv = *(const int4*)(qwrow + (kk >> 3) + bhalf * 4);
        const int g  = kk >> 7;
        const int zq = (qzrow[g >> 3] >> ((g & 7) * 4)) & 15;
        const float sf = srow[g];
        const float zs = (float)zq * sf;
        const int vs[4] = {qv.x, qv.y, qv.z, qv.w};
        bf16x8 wregs[4];
#pragma unroll
        for (int w = 0; w < 4; ++w) {
            const int v = vs[w];
#pragma unroll
            for (int j = 0; j < 8; ++j) {
                const float q = (float)((v >> (4 * j)) & 15);
                wregs[w][j] = (__bf16)(q * sf - zs);
            }
        }

#pragma unroll
        for (int it = 0; it < 4; ++it) {
            const int cs = acch[it] ^ (arow[it] & 7);
            *((bf16x8*)(As + (size_t)arow[it] * BK + cs * 8)) = areg[it];
        }
#pragma unroll
        for (int w = 0; w < 4; ++w) {
            const int cs = (bhalf * 4 + w) ^ (rb & 7);
            *((bf16x8*)(Bs + (size_t)rb * BK + cs * 8)) = wregs[w];
        }

        __syncthreads();

#pragma unroll
        for (int ks = 0; ks < 2; ++ks) {
            bf16x8 af[4], bfr[4];
#pragma unroll
            for (int mi = 0; mi < 4; ++mi) {
                const int row = wm * 64 + mi * 16 + (lane & 15);
                const int cs  = (ks * 4 + (lane >> 4)) ^ (row & 7);
                af[mi] = *((const bf16x8*)(As + (size_t)row * BK + cs * 8));
            }
#pragma unroll
            for (int ni = 0; ni < 4; ++ni) {
                const int row = wn * 64 + ni * 16 + (lane & 15);
                const int cs  = (ks * 4 + (lane >> 4)) ^ (row & 7);
                bfr[ni] = *((const bf16x8*)(Bs + (size_t)row * BK + cs * 8));
            }
#pragma unroll
            for (int mi = 0; mi < 4; ++mi)
#pragma unroll
                for (int ni = 0; ni < 4; ++ni)
                    acc[mi][ni] = __builtin_amdgcn_mfma_f32_16x16x32_bf16(
                        af[mi], bfr[ni], acc[mi][ni], 0, 0, 0);
        }
        __syncthreads();
    }

    const int cr0 = brow + wm * 64;
    const int cc0 = bcol + wn * 64;
#pragma unroll
    for (int ni = 0; ni < 4; ++ni) {
        const int col = cc0 + ni * 16 + (lane & 15);
        const float bv = Bi[col];
#pragma unroll
        for (int mi = 0; mi < 4; ++mi) {
#pragma unroll
            for (int r = 0; r < 4; ++r) {
                const int row = cr0 + mi * 16 + (lane >> 4) * 4 + r;
                Out[(size_t)row * N + col] = acc[mi][ni][r] + bv;
            }
        }
    }
}

extern "C" void kernel_launch(void* const* d_in, const int* in_sizes, int n_in,
                              void* d_out, int out_size, void* d_ws, size_t ws_size,
                              hipStream_t stream) {
    const float* X  = (const float*)d_in[0];
    const int*   QW = (const int*)d_in[1];
    const int*   QZ = (const int*)d_in[2];
    const float* S  = (const float*)d_in[3];
    const float* Bi = (const float*)d_in[4];
    float*       Out = (float*)d_out;

    const int O = in_sizes[4];           // 11008
    const int K = in_sizes[1] / O * 8;   // 4096
    const int M = in_sizes[0] / K;       // 8192
    const int NG = K / 128;

    // ws layout: Xq [M*K i8] | sx [M f32] | Wq [O*K i8] | St [NG*O f32]
    const size_t oXq = 0;
    const size_t oSx = (size_t)M * K;
    const size_t oWq = oSx + (size_t)M * 4;
    const size_t oSt = oWq + (size_t)O * K;
    const size_t need = oSt + (size_t)NG * O * 4;

    const bool shapes_ok = (M % JBM == 0) && (O % JBN == 0) &&
                           (K % 256 == 0) && (NG >= 4) &&
                           (oWq % 16 == 0) && (oSt % 16 == 0);

    if (ws_size >= need && shapes_ok) {
        int8_t* Xq = (int8_t*)d_ws + oXq;
        float*  sx = (float*)((char*)d_ws + oSx);
        int8_t* Wq = (int8_t*)d_ws + oWq;
        float*  St = (float*)((char*)d_ws + oSt);
        quant_x<<<M, 256, 0, stream>>>(X, Xq, sx, K);
        quant_w<<<O, K / 32, 0, stream>>>(QW, QZ, Wq, O, K);
        tr_s<<<(O * NG + 255) / 256, 256, 0, stream>>>(S, St, O, NG);
        const int grid = (M / JBM) * (O / JBN);   // 64*86 = 5504
        gemm_i8v2<<<grid, 512, 0, stream>>>(Xq, sx, Wq, St, Bi, Out, M, O, K);
    } else {
        const int grid = (M / BM) * (O / BN);
        awq_gemm_fused<<<grid, 256, 0, stream>>>(X, QW, QZ, S, Bi, Out, M, O, K);
    }
}

// Round 11
// 782.457 us; speedup vs baseline: 2.2190x; 2.2190x over previous
//
#include <hip/hip_runtime.h>
#include <hip/hip_bf16.h>
#include <stdint.h>

typedef __attribute__((ext_vector_type(8))) __bf16 bf16x8;
typedef __attribute__((ext_vector_type(4))) float f32x4;
typedef __attribute__((ext_vector_type(4))) int   i32x4;

#define BM 128
#define BN 128
#define BK 64

// i8 GEMM v2: 128x128 block, K-tile 64, group = 2 tiles (128 = AWQ group), ring-4 LDS (64KB)
#define JBM 128
#define JBN 128
#define JBK 64

__device__ inline void gload_lds16(const void* g, void* l) {
    __builtin_amdgcn_global_load_lds(
        (const __attribute__((address_space(1))) uint32_t*)g,
        (__attribute__((address_space(3))) uint32_t*)l, 16, 0, 0);
}

// ---------------- pass 1a: X f32 -> per-row int8 + scale ----------------
__global__ __launch_bounds__(256)
void quant_x(const float* __restrict__ X, int8_t* __restrict__ Xq,
             float* __restrict__ sx, int K) {
    const int row = blockIdx.x;
    const int tid = threadIdx.x;
    const float* base = X + (size_t)row * K;
    __shared__ float wred[4];

    float am = 0.f;
    for (int b = tid * 16; b < K; b += 256 * 16) {
#pragma unroll
        for (int c = 0; c < 4; ++c) {
            const float4 v = *(const float4*)(base + b + c * 4);
            am = fmaxf(am, fmaxf(fmaxf(fabsf(v.x), fabsf(v.y)),
                                 fmaxf(fabsf(v.z), fabsf(v.w))));
        }
    }
#pragma unroll
    for (int off = 32; off >= 1; off >>= 1)
        am = fmaxf(am, __shfl_xor(am, off));
    if ((tid & 63) == 0) wred[tid >> 6] = am;
    __syncthreads();
    am = fmaxf(fmaxf(wred[0], wred[1]), fmaxf(wred[2], wred[3]));

    const float inv = am > 0.f ? 127.f / am : 0.f;
    for (int b = tid * 16; b < K; b += 256 * 16) {
        int w[4];
#pragma unroll
        for (int c = 0; c < 4; ++c) {
            const float4 v = *(const float4*)(base + b + c * 4);
            const int b0 = __float2int_rn(v.x * inv) & 0xFF;
            const int b1 = __float2int_rn(v.y * inv) & 0xFF;
            const int b2 = __float2int_rn(v.z * inv) & 0xFF;
            const int b3 = __float2int_rn(v.w * inv) & 0xFF;
            w[c] = b0 | (b1 << 8) | (b2 << 16) | (b3 << 24);
        }
        *(int4*)(Xq + (size_t)row * K + b) = make_int4(w[0], w[1], w[2], w[3]);
    }
    if (tid == 0) sx[row] = am > 0.f ? am / 127.f : 0.f;
}

// ---------------- pass 1b: W -> int8 (q - z), exact ----------------
__global__ __launch_bounds__(128)
void quant_w(const int* __restrict__ QW, const int* __restrict__ QZ,
             int8_t* __restrict__ Wq, int N, int K) {
    const int PQ = K >> 3, NG = K >> 7, ZS = (NG + 7) >> 3;
    const int o = blockIdx.x;
    const int c = threadIdx.x;            // 0..K/32-1
    const int g = c >> 2;
    const int zq = (QZ[(size_t)o * ZS + (g >> 3)] >> ((g & 7) * 4)) & 15;
    const int4 qv = *(const int4*)(QW + (size_t)o * PQ + c * 4);
    const int vs[4] = {qv.x, qv.y, qv.z, qv.w};
    int words[8];
#pragma unroll
    for (int w = 0; w < 4; ++w) {
        const int v = vs[w];
        int w0 = 0, w1 = 0;
#pragma unroll
        for (int j = 0; j < 4; ++j)
            w0 |= ((((v >> (4 * j)) & 15) - zq) & 0xFF) << (8 * j);
#pragma unroll
        for (int j = 0; j < 4; ++j)
            w1 |= ((((v >> (4 * (j + 4))) & 15) - zq) & 0xFF) << (8 * j);
        words[w * 2] = w0; words[w * 2 + 1] = w1;
    }
    int8_t* dst = Wq + (size_t)o * K + c * 32;
    *(int4*)dst        = make_int4(words[0], words[1], words[2], words[3]);
    *(int4*)(dst + 16) = make_int4(words[4], words[5], words[6], words[7]);
}

// ---------------- pass 1c: scales [O][NG] f32 -> [NG][O] ----------------
__global__ __launch_bounds__(256)
void tr_s(const float* __restrict__ S, float* __restrict__ St, int N, int NG) {
    const int idx = blockIdx.x * 256 + threadIdx.x;
    if (idx >= N * NG) return;
    const int g = idx / N, o = idx % N;
    St[idx] = S[(size_t)o * NG + g];
}

// ---------------- pass 2: i8 GEMM v2 ----------------
// 512 thr = 8 waves (2 wm x 4 wn), wave tile 64x32 = 4x2 frags.
// Ring-4 x (A 128x64 i8 8KB + B 128x64 8KB) = 64KB -> 2 blocks/CU (4 waves/SIMD).
// __launch_bounds__(512, 2): observed toolchain semantics = CUDA minBlocksPerCU;
// (512,4) capped VGPR at 64 -> scratch-spill storm (r10: WRITE 3.1GB, 8.7% Mfma).
// (512,2) caps at 128 -> fits (facc32+iacc32+frags24+addr~12 ~ 100), 2 blocks/CU.
// Group g = K-tiles 2g,2g+1 (128 K = one AWQ group); iacc accumulates over both
// tiles (exact), one f32 merge per group. Depth-2 prefetch; counted gates
// (FIFO-audited): even-top vmcnt(2), odd-top vmcnt(4), CVT vmcnt(4); full drain
// only in peeled last group. Read swizzle chunk^((row>>1)&3) (r6: 0 conflicts),
// staging pre-swizzled at the global source, linear gload_lds dest.
__global__ __launch_bounds__(512, 2)
void gemm_i8v2(const int8_t* __restrict__ Aq, const float* __restrict__ sx,
               const int8_t* __restrict__ Bq, const float* __restrict__ St,
               const float* __restrict__ Bi, float* __restrict__ Out,
               int M, int N, int K) {
    __shared__ __align__(16) char lds[4 * 16384];

    const int tid  = threadIdx.x;
    const int lane = tid & 63;
    const int wid  = tid >> 6;
    const int wm   = wid >> 2;   // 0..1
    const int wn   = wid & 3;    // 0..3

    int bid = blockIdx.x;
    {
        const int nwg = gridDim.x;
        if ((nwg & 7) == 0) {
            const int cpx = nwg >> 3;
            bid = (bid & 7) * cpx + (bid >> 3);
        }
    }
    const int nbm  = M / JBM;
    const int brow = (bid % nbm) * JBM;   // col-major tile order
    const int bcol = (bid / nbm) * JBN;

    // staging: per matrix 512 16B-slots (1/thread). slot s: row=s>>2, c_lds=s&3,
    // global chunk c_g = (s&3) ^ ((s>>3)&3)   [row>>1 = s>>3]
    const int sro = tid >> 2;
    const int scg = (tid & 3) ^ ((tid >> 3) & 3);
    const int8_t* gA = Aq + (size_t)(brow + sro) * K + scg * 16;
    const int8_t* gB = Bq + (size_t)(bcol + sro) * K + scg * 16;
    const int lbA = wid * 1024;           // wave-uniform LDS byte base (HW adds lane*16)

    const int rA15 = lane & 15;
    const int q4   = lane >> 4;
    const int chunkoff = (q4 ^ ((rA15 >> 1) & 3)) * 16;

    f32x4 facc[4][2];
#pragma unroll
    for (int i = 0; i < 4; ++i) {
        facc[i][0] = {0.f, 0.f, 0.f, 0.f};
        facc[i][1] = {0.f, 0.f, 0.f, 0.f};
    }
    i32x4 iacc[4][2];
    float sv0 = 0.f, sv1 = 0.f;

    const int NGRP = K / 128;   // host guarantees even, >= 4

#define SBAR __builtin_amdgcn_sched_barrier(0)
#define ABUF(RR_) (lds + (RR_) * 16384)
#define BBUF(RR_) (lds + (RR_) * 16384 + 8192)

#define STAGE(RR_, T_)                                                   \
    do {                                                                 \
        gload_lds16(gA + (size_t)(T_) * JBK, ABUF(RR_) + lbA);           \
        gload_lds16(gB + (size_t)(T_) * JBK, BBUF(RR_) + lbA);           \
    } while (0)

#define LDA(RR_, MI) \
    (*(const i32x4*)(ABUF(RR_) + (wm * 64 + (MI) * 16 + rA15) * 64 + chunkoff))
#define LDB(RR_, NI) \
    (*(const i32x4*)(BBUF(RR_) + (wn * 32 + (NI) * 16 + rA15) * 64 + chunkoff))

#define MFMA8(RR_, FIRST_)                                               \
    do {                                                                 \
        i32x4 b0 = LDB(RR_, 0), b1 = LDB(RR_, 1);                        \
        i32x4 a0 = LDA(RR_, 0), a1 = LDA(RR_, 1);                        \
        i32x4 a2 = LDA(RR_, 2), a3 = LDA(RR_, 3);                        \
        asm volatile("s_waitcnt lgkmcnt(0)" ::: "memory"); SBAR;         \
        __builtin_amdgcn_s_setprio(1);                                   \
        if (FIRST_) {                                                    \
            const i32x4 zz = {0, 0, 0, 0};                               \
            iacc[0][0] = __builtin_amdgcn_mfma_i32_16x16x64_i8(a0, b0, zz, 0, 0, 0); \
            iacc[0][1] = __builtin_amdgcn_mfma_i32_16x16x64_i8(a0, b1, zz, 0, 0, 0); \
            iacc[1][0] = __builtin_amdgcn_mfma_i32_16x16x64_i8(a1, b0, zz, 0, 0, 0); \
            iacc[1][1] = __builtin_amdgcn_mfma_i32_16x16x64_i8(a1, b1, zz, 0, 0, 0); \
            iacc[2][0] = __builtin_amdgcn_mfma_i32_16x16x64_i8(a2, b0, zz, 0, 0, 0); \
            iacc[2][1] = __builtin_amdgcn_mfma_i32_16x16x64_i8(a2, b1, zz, 0, 0, 0); \
            iacc[3][0] = __builtin_amdgcn_mfma_i32_16x16x64_i8(a3, b0, zz, 0, 0, 0); \
            iacc[3][1] = __builtin_amdgcn_mfma_i32_16x16x64_i8(a3, b1, zz, 0, 0, 0); \
        } else {                                                         \
            iacc[0][0] = __builtin_amdgcn_mfma_i32_16x16x64_i8(a0, b0, iacc[0][0], 0, 0, 0); \
            iacc[0][1] = __builtin_amdgcn_mfma_i32_16x16x64_i8(a0, b1, iacc[0][1], 0, 0, 0); \
            iacc[1][0] = __builtin_amdgcn_mfma_i32_16x16x64_i8(a1, b0, iacc[1][0], 0, 0, 0); \
            iacc[1][1] = __builtin_amdgcn_mfma_i32_16x16x64_i8(a1, b1, iacc[1][1], 0, 0, 0); \
            iacc[2][0] = __builtin_amdgcn_mfma_i32_16x16x64_i8(a2, b0, iacc[2][0], 0, 0, 0); \
            iacc[2][1] = __builtin_amdgcn_mfma_i32_16x16x64_i8(a2, b1, iacc[2][1], 0, 0, 0); \
            iacc[3][0] = __builtin_amdgcn_mfma_i32_16x16x64_i8(a3, b0, iacc[3][0], 0, 0, 0); \
            iacc[3][1] = __builtin_amdgcn_mfma_i32_16x16x64_i8(a3, b1, iacc[3][1], 0, 0, 0); \
        }                                                                \
        __builtin_amdgcn_s_setprio(0); SBAR;                             \
    } while (0)

// GROUP: even tile (ring RE_) + odd tile (ring RO_) for group G_.
// S1_/S2_ stage future tiles; TOPE_/TOPO_/CVT_ are vmcnt literals (strings).
#define GROUP(RE_, RO_, G_, S1_, S2_, TOPE_, TOPO_, CVT_)                \
    do {                                                                 \
        asm volatile("s_waitcnt vmcnt(" TOPE_ ")" ::: "memory"); SBAR;   \
        __builtin_amdgcn_s_barrier(); SBAR;                              \
        {                                                                \
            const size_t so = (size_t)(G_) * N + bcol + wn * 32 + rA15;  \
            sv0 = St[so]; sv1 = St[so + 16];                             \
        }                                                                \
        SBAR; S1_; SBAR;                                                 \
        MFMA8(RE_, true);                                                \
        asm volatile("s_waitcnt vmcnt(" TOPO_ ")" ::: "memory"); SBAR;   \
        __builtin_amdgcn_s_barrier(); SBAR;                              \
        S2_; SBAR;                                                       \
        MFMA8(RO_, false);                                               \
        asm volatile("s_waitcnt vmcnt(" CVT_ ")" ::: "memory"); SBAR;    \
        _Pragma("unroll")                                                \
        for (int mi = 0; mi < 4; ++mi) {                                 \
            _Pragma("unroll")                                            \
            for (int j = 0; j < 4; ++j) {                                \
                facc[mi][0][j] += (float)iacc[mi][0][j] * sv0;           \
                facc[mi][1][j] += (float)iacc[mi][1][j] * sv1;           \
            }                                                            \
        }                                                                \
    } while (0)

    // prologue: tiles 0,1 in flight
    STAGE(0, 0);
    STAGE(1, 1);

    for (int g = 0; g < NGRP - 2; g += 2) {
        GROUP(0, 1, g,     STAGE(2, 2 * g + 2), STAGE(3, 2 * g + 3), "2", "4", "4");
        GROUP(2, 3, g + 1, STAGE(0, 2 * g + 4), STAGE(1, 2 * g + 5), "2", "4", "4");
    }
    GROUP(0, 1, NGRP - 2, STAGE(2, 2 * NGRP - 2), STAGE(3, 2 * NGRP - 1), "2", "4", "4");
    GROUP(2, 3, NGRP - 1, (void)0, (void)0, "2", "2", "0");

#undef GROUP
#undef MFMA8
#undef LDB
#undef LDA
#undef STAGE
#undef BBUF
#undef ABUF
#undef SBAR

    // epilogue: C frag col=lane&15, row=(lane>>4)*4+r; out = sx[row]*acc + bias
    const int cr0 = brow + wm * 64;
    const int cc0 = bcol + wn * 32;
    float sxr[4][4];
#pragma unroll
    for (int mi = 0; mi < 4; ++mi)
#pragma unroll
        for (int r = 0; r < 4; ++r)
            sxr[mi][r] = sx[cr0 + mi * 16 + q4 * 4 + r];
#pragma unroll
    for (int ni = 0; ni < 2; ++ni) {
        const int col = cc0 + ni * 16 + rA15;
        const float bv = Bi[col];
#pragma unroll
        for (int mi = 0; mi < 4; ++mi) {
#pragma unroll
            for (int r = 0; r < 4; ++r) {
                const int row = cr0 + mi * 16 + q4 * 4 + r;
                Out[(size_t)row * N + col] = sxr[mi][r] * facc[mi][ni][r] + bv;
            }
        }
    }
}

// ---------------- fallback: fused kernel (ws too small / odd shapes) ----------------
__global__ __launch_bounds__(256, 3)
void awq_gemm_fused(const float* __restrict__ X,
                    const int* __restrict__ QW,
                    const int* __restrict__ QZ,
                    const float* __restrict__ S,
                    const float* __restrict__ Bi,
                    float* __restrict__ Out,
                    int M, int N, int K) {
    const int PQ = K >> 3, NG = K >> 7, ZS = (NG + 7) >> 3;

    __shared__ __align__(16) __bf16 As[BM * BK];
    __shared__ __align__(16) __bf16 Bs[BN * BK];

    const int tid  = threadIdx.x;
    const int lane = tid & 63;
    const int wid  = tid >> 6;

    const int nwg = gridDim.x;
    int bid = blockIdx.x;
    if ((nwg & 7) == 0) {
        const int cpx = nwg >> 3;
        bid = (bid & 7) * cpx + (bid >> 3);
    }
    const int nbn  = N / BN;
    const int brow = (bid / nbn) * BM;
    const int bcol = (bid % nbn) * BN;

    const int wm = wid >> 1;
    const int wn = wid & 1;

    f32x4 acc[4][4];
#pragma unroll
    for (int i = 0; i < 4; ++i)
#pragma unroll
        for (int j = 0; j < 4; ++j)
            acc[i][j] = {0.f, 0.f, 0.f, 0.f};

    int arow[4], acch[4];
#pragma unroll
    for (int it = 0; it < 4; ++it) {
        const int idx = it * 256 + tid;
        arow[it] = idx >> 3;
        acch[it] = idx & 7;
    }

    const int rb    = tid >> 1;
    const int bhalf = tid & 1;
    const int og    = bcol + rb;
    const int* qwrow = QW + (size_t)og * PQ;
    const int* qzrow = QZ + (size_t)og * ZS;
    const float* srow = S + (size_t)og * NG;

    for (int kk = 0; kk < K; kk += BK) {
        bf16x8 areg[4];
#pragma unroll
        for (int it = 0; it < 4; ++it) {
            const float* gx = X + (size_t)(brow + arow[it]) * K + kk + acch[it] * 8;
            const float4 x0 = *(const float4*)gx;
            const float4 x1 = *(const float4*)(gx + 4);
            areg[it][0] = (__bf16)x0.x; areg[it][1] = (__bf16)x0.y;
            areg[it][2] = (__bf16)x0.z; areg[it][3] = (__bf16)x0.w;
            areg[it][4] = (__bf16)x1.x; areg[it][5] = (__bf16)x1.y;
            areg[it][6] = (__bf16)x1.z; areg[it][7] = (__bf16)x1.w;
        }

        const int4 qv = *(const int4*)(qwrow + (kk >> 3) + bhalf * 4);
        const int g  = kk >> 7;
        const int zq = (qzrow[g >> 3] >> ((g & 7) * 4)) & 15;
        const float sf = srow[g];
        const float zs = (float)zq * sf;
        const int vs[4] = {qv.x, qv.y, qv.z, qv.w};
        bf16x8 wregs[4];
#pragma unroll
        for (int w = 0; w < 4; ++w) {
            const int v = vs[w];
#pragma unroll
            for (int j = 0; j < 8; ++j) {
                const float q = (float)((v >> (4 * j)) & 15);
                wregs[w][j] = (__bf16)(q * sf - zs);
            }
        }

#pragma unroll
        for (int it = 0; it < 4; ++it) {
            const int cs = acch[it] ^ (arow[it] & 7);
            *((bf16x8*)(As + (size_t)arow[it] * BK + cs * 8)) = areg[it];
        }
#pragma unroll
        for (int w = 0; w < 4; ++w) {
            const int cs = (bhalf * 4 + w) ^ (rb & 7);
            *((bf16x8*)(Bs + (size_t)rb * BK + cs * 8)) = wregs[w];
        }

        __syncthreads();

#pragma unroll
        for (int ks = 0; ks < 2; ++ks) {
            bf16x8 af[4], bfr[4];
#pragma unroll
            for (int mi = 0; mi < 4; ++mi) {
                const int row = wm * 64 + mi * 16 + (lane & 15);
                const int cs  = (ks * 4 + (lane >> 4)) ^ (row & 7);
                af[mi] = *((const bf16x8*)(As + (size_t)row * BK + cs * 8));
            }
#pragma unroll
            for (int ni = 0; ni < 4; ++ni) {
                const int row = wn * 64 + ni * 16 + (lane & 15);
                const int cs  = (ks * 4 + (lane >> 4)) ^ (row & 7);
                bfr[ni] = *((const bf16x8*)(Bs + (size_t)row * BK + cs * 8));
            }
#pragma unroll
            for (int mi = 0; mi < 4; ++mi)
#pragma unroll
                for (int ni = 0; ni < 4; ++ni)
                    acc[mi][ni] = __builtin_amdgcn_mfma_f32_16x16x32_bf16(
                        af[mi], bfr[ni], acc[mi][ni], 0, 0, 0);
        }
        __syncthreads();
    }

    const int cr0 = brow + wm * 64;
    const int cc0 = bcol + wn * 64;
#pragma unroll
    for (int ni = 0; ni < 4; ++ni) {
        const int col = cc0 + ni * 16 + (lane & 15);
        const float bv = Bi[col];
#pragma unroll
        for (int mi = 0; mi < 4; ++mi) {
#pragma unroll
            for (int r = 0; r < 4; ++r) {
                const int row = cr0 + mi * 16 + (lane >> 4) * 4 + r;
                Out[(size_t)row * N + col] = acc[mi][ni][r] + bv;
            }
        }
    }
}

extern "C" void kernel_launch(void* const* d_in, const int* in_sizes, int n_in,
                              void* d_out, int out_size, void* d_ws, size_t ws_size,
                              hipStream_t stream) {
    const float* X  = (const float*)d_in[0];
    const int*   QW = (const int*)d_in[1];
    const int*   QZ = (const int*)d_in[2];
    const float* S  = (const float*)d_in[3];
    const float* Bi = (const float*)d_in[4];
    float*       Out = (float*)d_out;

    const int O = in_sizes[4];           // 11008
    const int K = in_sizes[1] / O * 8;   // 4096
    const int M = in_sizes[0] / K;       // 8192
    const int NG = K / 128;

    // ws layout: Xq [M*K i8] | sx [M f32] | Wq [O*K i8] | St [NG*O f32]
    const size_t oXq = 0;
    const size_t oSx = (size_t)M * K;
    const size_t oWq = oSx + (size_t)M * 4;
    const size_t oSt = oWq + (size_t)O * K;
    const size_t need = oSt + (size_t)NG * O * 4;

    const bool shapes_ok = (M % JBM == 0) && (O % JBN == 0) &&
                           (K % 256 == 0) && (NG >= 4) &&
                           (oWq % 16 == 0) && (oSt % 16 == 0);

    if (ws_size >= need && shapes_ok) {
        int8_t* Xq = (int8_t*)d_ws + oXq;
        float*  sx = (float*)((char*)d_ws + oSx);
        int8_t* Wq = (int8_t*)d_ws + oWq;
        float*  St = (float*)((char*)d_ws + oSt);
        quant_x<<<M, 256, 0, stream>>>(X, Xq, sx, K);
        quant_w<<<O, K / 32, 0, stream>>>(QW, QZ, Wq, O, K);
        tr_s<<<(O * NG + 255) / 256, 256, 0, stream>>>(S, St, O, NG);
        const int grid = (M / JBM) * (O / JBN);   // 64*86 = 5504
        gemm_i8v2<<<grid, 512, 0, stream>>>(Xq, sx, Wq, St, Bi, Out, M, O, K);
    } else {
        const int grid = (M / BM) * (O / BN);
        awq_gemm_fused<<<grid, 256, 0, stream>>>(X, QW, QZ, S, Bi, Out, M, O, K);
    }
}